// Round 1
// baseline (505.363 us; speedup 1.0000x reference)
//
#include <hip/hip_runtime.h>
#include <hip/hip_cooperative_groups.h>
#include <math.h>

namespace cg = cooperative_groups;

// HiPPO-LegS kernel: K[d, l] = C[d]^T A_bar^l B_bar[d], D=1024, N=64, L=4096.
// l = 64q + r decomposition; G_r = A_bar^r, H_q = (A_bar^64)^q via squarings
// S_j = A_bar^(2^j), j=0..11.  All products: mfma_f32_16x16x32_bf16 with
// split-bf16 hi/lo 3-term.
// Round 10: single cooperative kernel (4 phases, 3 grid syncs) replacing the
// 4-kernel chain. Evidence: top-5 rocprof rows are all 48.6us 256MiB ws-poison
// fills (2/iter ~= 97us of the 127us window); controllable kernel+gap budget
// is ~30us of which ~6-12us was inter-kernel launch/drain. Phases are kept
// bit-identical to R7/R9 math; LDS shrunk 74->37.4 KB (in-place squaring,
// single-buffered chains) so expand/contract phases keep 4 blocks/CU.

#define BPAD 72  // bf16 LDS row stride in ushorts (144 B)
#define ARR (64 * BPAD)

// ws layout (float offsets).
#define WS_BBAR   16                      // 1024x64 fp32
#define WS_SPL    65552                   // 12 x 8192: [hi|lo|thi|tlo] x 2048 floats
#define WS_MV     (WS_SPL + 12*8192)      // MvHi 2048, MvLo 2048
#define WS_GT     (WS_MV + 4096)          // 64 x 4096 (hi 2048 | lo 2048)
#define WS_H      (WS_GT + 64*4096)       // 64 x 4096 (hi | lo)
#define WS_W      (WS_H + 64*4096)        // [d][r][n] fp32
#define WS_X      (WS_W + 1024*4096)      // [d][q][n] fp32

using bf16x8 = __attribute__((ext_vector_type(8))) short;
using f32x4v = __attribute__((ext_vector_type(4))) float;
typedef unsigned short ushort_t;

__device__ __forceinline__ ushort_t f2bf(float x) {
  unsigned u = __builtin_bit_cast(unsigned, x);
  return (ushort_t)((u + 0x7FFFu + ((u >> 16) & 1u)) >> 16);
}
__device__ __forceinline__ float bfhi(float x) {
  unsigned u = __builtin_bit_cast(unsigned, x);
  unsigned r = (u + 0x7FFFu + ((u >> 16) & 1u)) & 0xFFFF0000u;
  return __builtin_bit_cast(float, r);
}
__device__ __forceinline__ ushort_t* usp(float* ws, int foff) {
  return (ushort_t*)(ws + foff);
}
__device__ __forceinline__ const ushort_t* uspc(const float* ws, int foff) {
  return (const ushort_t*)(ws + foff);
}

// ---- MFMA 64x64x64: D[m][n] = sum_k A[m][k]*Bt[n][k], split-bf16 3-term ----
// A-layout LDS [m][k] (BPAD), Bt-layout LDS [n][k]. Wave w owns m in [16w,16w+16).
__device__ __forceinline__ void mm_frag(const ushort_t* __restrict__ Ah,
                                        const ushort_t* __restrict__ Al,
                                        const ushort_t* __restrict__ Bh,
                                        const ushort_t* __restrict__ Bl,
                                        int w, int lane, f32x4v acc[4]) {
  const int lm = lane & 15, quad = lane >> 4;
  const int ar = (16 * w + lm) * BPAD, ko = quad * 8;
#pragma unroll
  for (int nt = 0; nt < 4; ++nt) { acc[nt][0] = acc[nt][1] = acc[nt][2] = acc[nt][3] = 0.f; }
#pragma unroll
  for (int kc = 0; kc < 64; kc += 32) {
    const bf16x8 ahi = *(const bf16x8*)&Ah[ar + kc + ko];
    const bf16x8 alo = *(const bf16x8*)&Al[ar + kc + ko];
#pragma unroll
    for (int nt = 0; nt < 4; ++nt) {
      const int br = (16 * nt + lm) * BPAD + kc + ko;
      const bf16x8 bhi = *(const bf16x8*)&Bh[br];
      const bf16x8 blo = *(const bf16x8*)&Bl[br];
      acc[nt] = __builtin_amdgcn_mfma_f32_16x16x32_bf16(ahi, bhi, acc[nt], 0, 0, 0);
      acc[nt] = __builtin_amdgcn_mfma_f32_16x16x32_bf16(ahi, blo, acc[nt], 0, 0, 0);
      acc[nt] = __builtin_amdgcn_mfma_f32_16x16x32_bf16(alo, bhi, acc[nt], 0, 0, 0);
    }
  }
}

// D regs -> split bf16 LDS in BOTH layouts (used by the in-place squarings).
__device__ __forceinline__ void dstore_lds(const f32x4v acc[4],
                                           ushort_t* __restrict__ Ah, ushort_t* __restrict__ Al,
                                           ushort_t* __restrict__ Bth, ushort_t* __restrict__ Btl,
                                           int w, int lane) {
  const int lm = lane & 15, quad = lane >> 4;
  const int m0 = 16 * w + 4 * quad;
#pragma unroll
  for (int nt = 0; nt < 4; ++nt) {
    const int n = 16 * nt + lm;
    ushort_t h[4], l[4];
#pragma unroll
    for (int reg = 0; reg < 4; ++reg) {
      const float x = acc[nt][reg];
      h[reg] = f2bf(x); l[reg] = f2bf(x - bfhi(x));
      Ah[(m0 + reg) * BPAD + n] = h[reg];
      Al[(m0 + reg) * BPAD + n] = l[reg];
    }
    uint2 hp, lp;
    hp.x = (unsigned)h[0] | ((unsigned)h[1] << 16);
    hp.y = (unsigned)h[2] | ((unsigned)h[3] << 16);
    lp.x = (unsigned)l[0] | ((unsigned)l[1] << 16);
    lp.y = (unsigned)l[2] | ((unsigned)l[3] << 16);
    *(uint2*)&Bth[n * BPAD + m0] = hp;
    *(uint2*)&Btl[n * BPAD + m0] = lp;
  }
}

// A-layout-only variant (chain intermediate results).
__device__ __forceinline__ void dstore_A(const f32x4v acc[4],
                                         ushort_t* __restrict__ Ah, ushort_t* __restrict__ Al,
                                         int w, int lane) {
  const int lm = lane & 15, quad = lane >> 4;
  const int m0 = 16 * w + 4 * quad;
#pragma unroll
  for (int nt = 0; nt < 4; ++nt) {
    const int n = 16 * nt + lm;
#pragma unroll
    for (int reg = 0; reg < 4; ++reg) {
      const float x = acc[nt][reg];
      Ah[(m0 + reg) * BPAD + n] = f2bf(x);
      Al[(m0 + reg) * BPAD + n] = f2bf(x - bfhi(x));
    }
  }
}

// Bt-layout-only variant (chain0 final result = transposed export).
__device__ __forceinline__ void dstore_Bt(const f32x4v acc[4],
                                          ushort_t* __restrict__ Bth, ushort_t* __restrict__ Btl,
                                          int w, int lane) {
  const int lm = lane & 15, quad = lane >> 4;
  const int m0 = 16 * w + 4 * quad;
#pragma unroll
  for (int nt = 0; nt < 4; ++nt) {
    const int n = 16 * nt + lm;
    ushort_t h[4], l[4];
#pragma unroll
    for (int reg = 0; reg < 4; ++reg) {
      const float x = acc[nt][reg];
      h[reg] = f2bf(x); l[reg] = f2bf(x - bfhi(x));
    }
    uint2 hp, lp;
    hp.x = (unsigned)h[0] | ((unsigned)h[1] << 16);
    hp.y = (unsigned)h[2] | ((unsigned)h[3] << 16);
    lp.x = (unsigned)l[0] | ((unsigned)l[1] << 16);
    lp.y = (unsigned)l[2] | ((unsigned)l[3] << 16);
    *(uint2*)&Bth[n * BPAD + m0] = hp;
    *(uint2*)&Btl[n * BPAD + m0] = lp;
  }
}

// packed 64x64 ushort ws region <-> padded LDS (BPAD), 256 threads
__device__ __forceinline__ void cp_l2w(const ushort_t* __restrict__ l,
                                       ushort_t* __restrict__ g, int tid) {
  for (int e = tid; e < 512; e += 256) {
    const int row = e >> 3, c8 = (e & 7) * 8;
    *(uint4*)&g[row * 64 + c8] = *(const uint4*)&l[row * BPAD + c8];
  }
}
__device__ __forceinline__ void cp_w2l(const ushort_t* __restrict__ g,
                                       ushort_t* __restrict__ l, int tid) {
  for (int e = tid; e < 512; e += 256) {
    const int row = e >> 3, c8 = (e & 7) * 8;
    *(uint4*)&l[row * BPAD + c8] = *(const uint4*)&g[row * 64 + c8];
  }
}

// fp32 global 64x64 -> split bf16 A-layout LDS, 256 threads
__device__ __forceinline__ void split_stage(const float* __restrict__ g,
                                            ushort_t* __restrict__ Ah,
                                            ushort_t* __restrict__ Al, int tid) {
#pragma unroll
  for (int j = 0; j < 4; ++j) {
    const int flat = j * 1024 + tid * 4;
    const int row = flat >> 6, col = flat & 63;
    const float4 v = *(const float4*)&g[flat];
    ushort_t h0 = f2bf(v.x), h1 = f2bf(v.y), h2 = f2bf(v.z), h3 = f2bf(v.w);
    ushort_t l0 = f2bf(v.x - bfhi(v.x)), l1 = f2bf(v.y - bfhi(v.y));
    ushort_t l2 = f2bf(v.z - bfhi(v.z)), l3 = f2bf(v.w - bfhi(v.w));
    uint2 hp, lp;
    hp.x = (unsigned)h0 | ((unsigned)h1 << 16); hp.y = (unsigned)h2 | ((unsigned)h3 << 16);
    lp.x = (unsigned)l0 | ((unsigned)l1 << 16); lp.y = (unsigned)l2 | ((unsigned)l3 << 16);
    *(uint2*)&Ah[row * BPAD + col] = hp;
    *(uint2*)&Al[row * BPAD + col] = lp;
  }
}

// ---------------------------------------------------------------------------
// Fused cooperative kernel.
//  P1 (block 0): fp32 recursive-doubling inverse of lower-tri M; A_bar =
//     2*Minv - I; 11 in-place MFMA squarings; exports S_j / S_j^T / Minv.
//  P2 (blocks 0..143): G_r^T, H_q chains + B_bar (single-buffered products).
//  P3 (grid-stride, 2048 tiles): W = C @ G_r, X = Bbar @ H_q^T.
//  P4 (grid-stride, 1024 tiles): out[d][q*64+r] = sum_j X[q][j] W[r][j].
// LDS 37376 B -> 4 blocks/CU.
// ---------------------------------------------------------------------------
__global__ __launch_bounds__(256, 4) void k_fused(const float* __restrict__ A,
                                                  const float* __restrict__ Bg,
                                                  const float* __restrict__ Cg,
                                                  const float* __restrict__ Dg,
                                                  const float* __restrict__ logdt,
                                                  float* __restrict__ ws,
                                                  float* __restrict__ out,
                                                  int grid) {
  __shared__ __align__(16) char SM[37376];
  const int bid = blockIdx.x, tid = threadIdx.x;
  const int w = tid >> 6, lane = tid & 63;
  cg::grid_group gg = cg::this_grid();

  // ---------------- P1: setup (block 0 only) ----------------
  if (bid == 0) {
    float* Msh = (float*)SM;             // 64*65 fp32
    float* Tm  = (float*)(SM + 16640);   // 64*65 fp32 (becomes Minv)
    float* tmpb = (float*)(SM + 33280);  // 1024 fp32
    ushort_t* ping = (ushort_t*)SM;      // 4 x ARR, overlays all (after stash)

    const float hdt = 0.5f * expf(logdt[0]);
    for (int idx = tid; idx < 4096; idx += 256) {
      const int i = idx >> 6, j = idx & 63;
      Msh[i * 65 + j] = ((i == j) ? 1.f : 0.f) - hdt * A[idx];
      Tm[i * 65 + j] = 0.f;
    }
    __syncthreads();
    if (tid < 64) Tm[tid * 65 + tid] = 1.0f / Msh[tid * 65 + tid];
    __syncthreads();
    for (int lb = 0; lb < 6; ++lb) {
      const int b = 1 << lb;
      const int E = 32 * b;
      for (int e = tid; e < E; e += 256) {
        const int rem = e & (b * b - 1);
        const int p = e >> (2 * lb);
        const int i = rem >> lb, j = rem & (b - 1);
        const int c0 = p << (lb + 1), r0 = c0 + b;
        float s = 0.f;
        for (int k = 0; k < b; ++k)
          s += Msh[(r0 + i) * 65 + c0 + k] * Tm[(c0 + k) * 65 + c0 + j];
        tmpb[e] = s;
      }
      __syncthreads();
      for (int e = tid; e < E; e += 256) {
        const int rem = e & (b * b - 1);
        const int p = e >> (2 * lb);
        const int i = rem >> lb, j = rem & (b - 1);
        const int c0 = p << (lb + 1), r0 = c0 + b;
        float s = 0.f;
        const float* tp = &tmpb[e - rem];
        for (int k = 0; k < b; ++k)
          s += Tm[(r0 + i) * 65 + r0 + k] * tp[k * b + j];
        Tm[(r0 + i) * 65 + c0 + j] = -s;
      }
      __syncthreads();
    }

    // Export Minv; stash Minv values in regs (ping overlays Tm below).
    ushort_t* MvH = usp(ws, WS_MV);
    ushort_t* MvL = usp(ws, WS_MV + 2048);
    float mv[16];
#pragma unroll
    for (int t16 = 0; t16 < 16; ++t16) {
      const int idx = tid + 256 * t16;
      const float m = Tm[(idx >> 6) * 65 + (idx & 63)];
      mv[t16] = m;
      MvH[idx] = f2bf(m); MvL[idx] = f2bf(m - bfhi(m));
    }
    __syncthreads();  // all Tm reads done before ping overwrites it
#pragma unroll
    for (int t16 = 0; t16 < 16; ++t16) {
      const int idx = tid + 256 * t16;
      const int i = idx >> 6, j = idx & 63;
      const float v = 2.f * mv[t16] - ((i == j) ? 1.f : 0.f);
      const ushort_t h = f2bf(v), l2 = f2bf(v - bfhi(v));
      ping[0 * ARR + i * BPAD + j] = h; ping[1 * ARR + i * BPAD + j] = l2;
      ping[2 * ARR + j * BPAD + i] = h; ping[3 * ARR + j * BPAD + i] = l2;
    }
    __syncthreads();
    cp_l2w(ping + 0 * ARR, usp(ws, WS_SPL + 0), tid);
    cp_l2w(ping + 1 * ARR, usp(ws, WS_SPL + 2048), tid);
    cp_l2w(ping + 2 * ARR, usp(ws, WS_SPL + 4096), tid);
    cp_l2w(ping + 3 * ARR, usp(ws, WS_SPL + 6144), tid);

    for (int sj = 1; sj < 12; ++sj) {  // in-place squarings
      f32x4v acc[4];
      mm_frag(ping, ping + ARR, ping + 2 * ARR, ping + 3 * ARR, w, lane, acc);
      __syncthreads();  // all reads done before overwrite
      dstore_lds(acc, ping, ping + ARR, ping + 2 * ARR, ping + 3 * ARR, w, lane);
      __syncthreads();
      const int base = WS_SPL + sj * 8192;
      cp_l2w(ping + 0 * ARR, usp(ws, base + 0), tid);
      cp_l2w(ping + 1 * ARR, usp(ws, base + 2048), tid);
      cp_l2w(ping + 2 * ARR, usp(ws, base + 4096), tid);
      cp_l2w(ping + 3 * ARR, usp(ws, base + 6144), tid);
    }
  }
  __threadfence();
  gg.sync();
  __threadfence();

  ushort_t* ca  = (ushort_t*)SM;          // 2 x ARR
  ushort_t* Bst = (ushort_t*)SM + 2 * ARR;  // 2 x ARR

  // ---------------- P2: powers (blocks 0..143) ----------------
  if (bid < 128) {
    const int chain = bid >> 6, r = bid & 63;
    ushort_t* dstH = usp(ws, (chain ? WS_H : WS_GT) + r * 4096);
    ushort_t* dstL = usp(ws, (chain ? WS_H : WS_GT) + r * 4096 + 2048);
    if (r == 0) {  // identity
      for (int idx = tid; idx < 4096; idx += 256) {
        const int i = idx >> 6, j = idx & 63;
        dstH[idx] = (i == j) ? (ushort_t)0x3F80 : (ushort_t)0;
        dstL[idx] = 0;
      }
    } else {
      const int j0 = __ffs(r) - 1;
      if (r == (1 << j0)) {  // single bit: straight ws->ws copy
        const int sb = WS_SPL + (chain * 6 + j0) * 8192;
        const int src = chain ? sb : (sb + 4096);  // chain0: St, chain1: S
        const uint4* sh = (const uint4*)uspc(ws, src);
        const uint4* sl = (const uint4*)uspc(ws, src + 2048);
        uint4* dh = (uint4*)dstH;
        uint4* dl = (uint4*)dstL;
        for (int e = tid; e < 512; e += 256) { dh[e] = sh[e]; dl[e] = sl[e]; }
      } else {
        // multi-bit chain, single-buffered: ca accumulates product in A-layout
        const int sb0 = WS_SPL + (chain * 6 + j0) * 8192;
        cp_w2l(uspc(ws, sb0 + 0), ca, tid);
        cp_w2l(uspc(ws, sb0 + 2048), ca + ARR, tid);
        for (int j = j0 + 1; j < 6; ++j) {
          if ((r >> j) & 1) {
            __syncthreads();  // prior dstore into ca / prior Bst reads done
            const int sb = WS_SPL + (chain * 6 + j) * 8192;
            cp_w2l(uspc(ws, sb + 4096), Bst, tid);        // St_j hi
            cp_w2l(uspc(ws, sb + 6144), Bst + ARR, tid);  // St_j lo
            __syncthreads();
            f32x4v acc[4];
            mm_frag(ca, ca + ARR, Bst, Bst + ARR, w, lane, acc);
            __syncthreads();  // all reads done before overwrite
            const bool last = ((r >> (j + 1)) == 0);
            if (last && chain == 0)
              dstore_Bt(acc, Bst, Bst + ARR, w, lane);  // Bst dead -> holds Gt
            else
              dstore_A(acc, ca, ca + ARR, w, lane);
          }
        }
        __syncthreads();
        if (chain == 0) { cp_l2w(Bst, dstH, tid); cp_l2w(Bst + ARR, dstL, tid); }
        else           { cp_l2w(ca, dstH, tid);  cp_l2w(ca + ARR, dstL, tid); }
      }
    }
  } else if (bid < 144) {
    // B_bar chunk: dt * B_chunk @ Minv^T. Bt-frag rows = Minv rows.
    const int d0 = (bid - 128) * 64;
    const float dtv = expf(logdt[0]);
    split_stage(Bg + d0 * 64, ca, ca + ARR, tid);
    cp_w2l(uspc(ws, WS_MV), Bst, tid);
    cp_w2l(uspc(ws, WS_MV + 2048), Bst + ARR, tid);
    __syncthreads();
    f32x4v acc[4];
    mm_frag(ca, ca + ARR, Bst, Bst + ARR, w, lane, acc);
    const int lm = lane & 15, quad = lane >> 4;
    float* od = ws + WS_BBAR + d0 * 64;
#pragma unroll
    for (int nt = 0; nt < 4; ++nt)
#pragma unroll
      for (int reg = 0; reg < 4; ++reg)
        od[(16 * w + 4 * quad + reg) * 64 + 16 * nt + lm] = dtv * acc[nt][reg];
  }
  __threadfence();
  gg.sync();
  __threadfence();

  // ---------------- P3: expand (2048 tiles, grid-stride) ----------------
  for (int t = bid; t < 2048; t += grid) {
    const int chain = t >> 10, rr = (t >> 4) & 63, dch = t & 15;
    const int d0 = dch * 64;
    split_stage(chain ? (ws + WS_BBAR + d0 * 64) : (Cg + d0 * 64), ca, ca + ARR, tid);
    const int mb = (chain ? WS_H : WS_GT) + rr * 4096;
    cp_w2l(uspc(ws, mb + 0), Bst, tid);
    cp_w2l(uspc(ws, mb + 2048), Bst + ARR, tid);
    __syncthreads();
    f32x4v acc[4];
    mm_frag(ca, ca + ARR, Bst, Bst + ARR, w, lane, acc);
    const int lm = lane & 15, quad = lane >> 4;
    float* dst = ws + (chain ? WS_X : WS_W) + d0 * 4096 + rr * 64;
#pragma unroll
    for (int nt = 0; nt < 4; ++nt)
#pragma unroll
      for (int reg = 0; reg < 4; ++reg)
        dst[(16 * w + 4 * quad + reg) * 4096 + 16 * nt + lm] = acc[nt][reg];
    __syncthreads();  // before next tile overwrites LDS
  }
  __threadfence();
  gg.sync();
  __threadfence();

  // ---------------- P4: contract (1024 tiles, grid-stride) ----------------
  ushort_t* XhiL = (ushort_t*)SM;
  ushort_t* XloL = XhiL + ARR;
  ushort_t* WhiL = XhiL + 2 * ARR;
  ushort_t* WloL = XhiL + 3 * ARR;
  for (int t = bid; t < 1024; t += grid) {
    const float* Wg = ws + WS_W + t * 4096;
    const float* Xg = ws + WS_X + t * 4096;
#pragma unroll
    for (int j = 0; j < 4; ++j) {
      const int flat = j * 1024 + tid * 4;
      const int row = flat >> 6, col = flat & 63;
      const float4 wv = *(const float4*)&Wg[flat];
      const float4 xv = *(const float4*)&Xg[flat];
      const int o = row * BPAD + col;
#pragma unroll
      for (int s = 0; s < 2; ++s) {
        const float4 v = s ? xv : wv;
        ushort_t h0 = f2bf(v.x), h1 = f2bf(v.y), h2 = f2bf(v.z), h3 = f2bf(v.w);
        ushort_t l0 = f2bf(v.x - bfhi(v.x)), l1 = f2bf(v.y - bfhi(v.y));
        ushort_t l2 = f2bf(v.z - bfhi(v.z)), l3 = f2bf(v.w - bfhi(v.w));
        uint2 hp, lp;
        hp.x = (unsigned)h0 | ((unsigned)h1 << 16); hp.y = (unsigned)h2 | ((unsigned)h3 << 16);
        lp.x = (unsigned)l0 | ((unsigned)l1 << 16); lp.y = (unsigned)l2 | ((unsigned)l3 << 16);
        *(uint2*)&(s ? XhiL : WhiL)[o] = hp;
        *(uint2*)&(s ? XloL : WloL)[o] = lp;
      }
    }
    __syncthreads();

    const int lm = lane & 15, quad = lane >> 4;
    const int qrow = 16 * w + lm;
    const int koff = quad * 8;
    f32x4v acc[4];
#pragma unroll
    for (int nt = 0; nt < 4; ++nt) { acc[nt][0] = 0.f; acc[nt][1] = 0.f; acc[nt][2] = 0.f; acc[nt][3] = 0.f; }
#pragma unroll
    for (int kc = 0; kc < 64; kc += 32) {
      const bf16x8 ahi = *(const bf16x8*)&XhiL[qrow * BPAD + kc + koff];
      const bf16x8 alo = *(const bf16x8*)&XloL[qrow * BPAD + kc + koff];
#pragma unroll
      for (int nt = 0; nt < 4; ++nt) {
        const int rrow = 16 * nt + lm;
        const bf16x8 bhi = *(const bf16x8*)&WhiL[rrow * BPAD + kc + koff];
        const bf16x8 blo = *(const bf16x8*)&WloL[rrow * BPAD + kc + koff];
        acc[nt] = __builtin_amdgcn_mfma_f32_16x16x32_bf16(ahi, bhi, acc[nt], 0, 0, 0);
        acc[nt] = __builtin_amdgcn_mfma_f32_16x16x32_bf16(ahi, blo, acc[nt], 0, 0, 0);
        acc[nt] = __builtin_amdgcn_mfma_f32_16x16x32_bf16(alo, bhi, acc[nt], 0, 0, 0);
      }
    }
    if (tid == 0) acc[0][0] += Dg[t];

    float* od = out + t * 4096;
#pragma unroll
    for (int nt = 0; nt < 4; ++nt) {
#pragma unroll
      for (int reg = 0; reg < 4; ++reg) {
        const int q = 16 * w + quad * 4 + reg;
        od[q * 64 + 16 * nt + lm] = acc[nt][reg];
      }
    }
    __syncthreads();  // before next tile overwrites LDS
  }
}

extern "C" void kernel_launch(void* const* d_in, const int* in_sizes, int n_in,
                              void* d_out, int out_size, void* d_ws, size_t ws_size,
                              hipStream_t stream) {
  const float* A     = (const float*)d_in[0];  // A_ct 64x64
  const float* B     = (const float*)d_in[1];  // 1024x64
  const float* C     = (const float*)d_in[2];  // 1024x64
  const float* Dv    = (const float*)d_in[3];  // 1024
  const float* logdt = (const float*)d_in[4];  // scalar
  float* ws  = (float*)d_ws;
  float* out = (float*)d_out;                  // 1024*4096 fp32

  // Cooperative grid sized to guaranteed co-residency (query once, cache).
  static int grid_blocks = 0;
  if (grid_blocks == 0) {
    int nb = 0;
    if (hipOccupancyMaxActiveBlocksPerMultiprocessor(&nb, k_fused, 256, 0) != hipSuccess || nb < 1)
      nb = 2;  // conservative fallback: 37.4 KB LDS always fits 2/CU
    int g = nb * 256;  // 256 CUs on MI355X
    if (g > 1024) g = 1024;  // 1024 blocks covers max parallelism (P4 tiles)
    grid_blocks = g;
  }
  int grid = grid_blocks;
  void* args[] = {(void*)&A, (void*)&B, (void*)&C, (void*)&Dv,
                  (void*)&logdt, (void*)&ws, (void*)&out, (void*)&grid};
  hipLaunchCooperativeKernel(k_fused, dim3(grid), dim3(256), args, 0, stream);
}

// Round 2
// 119.592 us; speedup vs baseline: 4.2257x; 4.2257x over previous
//
#include <hip/hip_runtime.h>
#include <math.h>

// HiPPO-LegS kernel: K[d, l] = C[d]^T A_bar^l B_bar[d], D=1024, N=64, L=4096.
// l = 64q + r decomposition; G_r = A_bar^r, H_q = (A_bar^64)^q via squarings
// S_j = A_bar^(2^j), j=0..11.  All products: mfma_f32_16x16x32_bf16 with
// split-bf16 hi/lo 3-term.
// Round 11: cooperative fusion REVERTED (R10: grid.sync cost ~250us each on
// this stack -> 784us kernel). Back to the 4-kernel R9 structure. New vs R9:
// k_setup and k_powers widened to 1024 threads (16 waves, one 16x16 output
// tile per wave, 6 MFMA each) to cut the latency-bound serial prologue; the
// 11 squarings are ping/pong double-buffered with ONE barrier each.
// k_expand / k_contract are byte-identical to R9 (proven).

#define BPAD 72  // bf16 LDS row stride in ushorts (144 B)
#define ARR (64 * BPAD)

// ws layout (float offsets).
#define WS_BBAR   16                      // 1024x64 fp32
#define WS_SPL    65552                   // 12 x 8192: [hi|lo|thi|tlo] x 2048 floats
#define WS_MV     (WS_SPL + 12*8192)      // MvHi 2048, MvLo 2048
#define WS_GT     (WS_MV + 4096)          // 64 x 4096 (hi 2048 | lo 2048)
#define WS_H      (WS_GT + 64*4096)       // 64 x 4096 (hi | lo)
#define WS_W      (WS_H + 64*4096)        // [d][r][n] fp32
#define WS_X      (WS_W + 1024*4096)      // [d][q][n] fp32

using bf16x8 = __attribute__((ext_vector_type(8))) short;
using f32x4v = __attribute__((ext_vector_type(4))) float;
typedef unsigned short ushort_t;

__device__ __forceinline__ ushort_t f2bf(float x) {
  unsigned u = __builtin_bit_cast(unsigned, x);
  return (ushort_t)((u + 0x7FFFu + ((u >> 16) & 1u)) >> 16);
}
__device__ __forceinline__ float bfhi(float x) {
  unsigned u = __builtin_bit_cast(unsigned, x);
  unsigned r = (u + 0x7FFFu + ((u >> 16) & 1u)) & 0xFFFF0000u;
  return __builtin_bit_cast(float, r);
}
__device__ __forceinline__ ushort_t* usp(float* ws, int foff) {
  return (ushort_t*)(ws + foff);
}
__device__ __forceinline__ const ushort_t* uspc(const float* ws, int foff) {
  return (const ushort_t*)(ws + foff);
}

// ---- 4-wave MFMA 64x64x64 (k_expand/k_contract path, unchanged from R9) ----
__device__ __forceinline__ void mm_frag(const ushort_t* __restrict__ Ah,
                                        const ushort_t* __restrict__ Al,
                                        const ushort_t* __restrict__ Bh,
                                        const ushort_t* __restrict__ Bl,
                                        int w, int lane, f32x4v acc[4]) {
  const int lm = lane & 15, quad = lane >> 4;
  const int ar = (16 * w + lm) * BPAD, ko = quad * 8;
#pragma unroll
  for (int nt = 0; nt < 4; ++nt) { acc[nt][0] = acc[nt][1] = acc[nt][2] = acc[nt][3] = 0.f; }
#pragma unroll
  for (int kc = 0; kc < 64; kc += 32) {
    const bf16x8 ahi = *(const bf16x8*)&Ah[ar + kc + ko];
    const bf16x8 alo = *(const bf16x8*)&Al[ar + kc + ko];
#pragma unroll
    for (int nt = 0; nt < 4; ++nt) {
      const int br = (16 * nt + lm) * BPAD + kc + ko;
      const bf16x8 bhi = *(const bf16x8*)&Bh[br];
      const bf16x8 blo = *(const bf16x8*)&Bl[br];
      acc[nt] = __builtin_amdgcn_mfma_f32_16x16x32_bf16(ahi, bhi, acc[nt], 0, 0, 0);
      acc[nt] = __builtin_amdgcn_mfma_f32_16x16x32_bf16(ahi, blo, acc[nt], 0, 0, 0);
      acc[nt] = __builtin_amdgcn_mfma_f32_16x16x32_bf16(alo, bhi, acc[nt], 0, 0, 0);
    }
  }
}

// ---- 16-wave MFMA 64x64x64: wave (mt,nt) owns one 16x16 tile, 6 MFMA ----
__device__ __forceinline__ void mm_frag16(const ushort_t* __restrict__ Ah,
                                          const ushort_t* __restrict__ Al,
                                          const ushort_t* __restrict__ Bh,
                                          const ushort_t* __restrict__ Bl,
                                          int mt, int nt, int lane, f32x4v& acc) {
  const int lm = lane & 15, quad = lane >> 4;
  const int ar = (16 * mt + lm) * BPAD, br = (16 * nt + lm) * BPAD, ko = quad * 8;
  acc[0] = acc[1] = acc[2] = acc[3] = 0.f;
#pragma unroll
  for (int kc = 0; kc < 64; kc += 32) {
    const bf16x8 ahi = *(const bf16x8*)&Ah[ar + kc + ko];
    const bf16x8 alo = *(const bf16x8*)&Al[ar + kc + ko];
    const bf16x8 bhi = *(const bf16x8*)&Bh[br + kc + ko];
    const bf16x8 blo = *(const bf16x8*)&Bl[br + kc + ko];
    acc = __builtin_amdgcn_mfma_f32_16x16x32_bf16(ahi, bhi, acc, 0, 0, 0);
    acc = __builtin_amdgcn_mfma_f32_16x16x32_bf16(ahi, blo, acc, 0, 0, 0);
    acc = __builtin_amdgcn_mfma_f32_16x16x32_bf16(alo, bhi, acc, 0, 0, 0);
  }
}

// 16-wave D store -> split bf16, BOTH layouts.
__device__ __forceinline__ void dstore_lds16(const f32x4v& acc,
                                             ushort_t* __restrict__ Ah, ushort_t* __restrict__ Al,
                                             ushort_t* __restrict__ Bth, ushort_t* __restrict__ Btl,
                                             int mt, int nt, int lane) {
  const int lm = lane & 15, quad = lane >> 4;
  const int m0 = 16 * mt + 4 * quad;
  const int n = 16 * nt + lm;
  ushort_t h[4], l[4];
#pragma unroll
  for (int reg = 0; reg < 4; ++reg) {
    const float x = acc[reg];
    h[reg] = f2bf(x); l[reg] = f2bf(x - bfhi(x));
    Ah[(m0 + reg) * BPAD + n] = h[reg];
    Al[(m0 + reg) * BPAD + n] = l[reg];
  }
  uint2 hp, lp;
  hp.x = (unsigned)h[0] | ((unsigned)h[1] << 16);
  hp.y = (unsigned)h[2] | ((unsigned)h[3] << 16);
  lp.x = (unsigned)l[0] | ((unsigned)l[1] << 16);
  lp.y = (unsigned)l[2] | ((unsigned)l[3] << 16);
  *(uint2*)&Bth[n * BPAD + m0] = hp;
  *(uint2*)&Btl[n * BPAD + m0] = lp;
}

// 16-wave D store -> A-layout only.
__device__ __forceinline__ void dstore_A16(const f32x4v& acc,
                                           ushort_t* __restrict__ Ah, ushort_t* __restrict__ Al,
                                           int mt, int nt, int lane) {
  const int lm = lane & 15, quad = lane >> 4;
  const int m0 = 16 * mt + 4 * quad;
  const int n = 16 * nt + lm;
#pragma unroll
  for (int reg = 0; reg < 4; ++reg) {
    const float x = acc[reg];
    Ah[(m0 + reg) * BPAD + n] = f2bf(x);
    Al[(m0 + reg) * BPAD + n] = f2bf(x - bfhi(x));
  }
}

// 16-wave D store -> Bt-layout only (packed).
__device__ __forceinline__ void dstore_Bt16(const f32x4v& acc,
                                            ushort_t* __restrict__ Bth, ushort_t* __restrict__ Btl,
                                            int mt, int nt, int lane) {
  const int lm = lane & 15, quad = lane >> 4;
  const int m0 = 16 * mt + 4 * quad;
  const int n = 16 * nt + lm;
  ushort_t h[4], l[4];
#pragma unroll
  for (int reg = 0; reg < 4; ++reg) {
    const float x = acc[reg];
    h[reg] = f2bf(x); l[reg] = f2bf(x - bfhi(x));
  }
  uint2 hp, lp;
  hp.x = (unsigned)h[0] | ((unsigned)h[1] << 16);
  hp.y = (unsigned)h[2] | ((unsigned)h[3] << 16);
  lp.x = (unsigned)l[0] | ((unsigned)l[1] << 16);
  lp.y = (unsigned)l[2] | ((unsigned)l[3] << 16);
  *(uint2*)&Bth[n * BPAD + m0] = hp;
  *(uint2*)&Btl[n * BPAD + m0] = lp;
}

// packed 64x64 ushort ws region <-> padded LDS (BPAD), NT threads
__device__ __forceinline__ void cp_l2w(const ushort_t* __restrict__ l,
                                       ushort_t* __restrict__ g, int tid, int NT) {
  for (int e = tid; e < 512; e += NT) {
    const int row = e >> 3, c8 = (e & 7) * 8;
    *(uint4*)&g[row * 64 + c8] = *(const uint4*)&l[row * BPAD + c8];
  }
}
__device__ __forceinline__ void cp_w2l(const ushort_t* __restrict__ g,
                                       ushort_t* __restrict__ l, int tid, int NT) {
  for (int e = tid; e < 512; e += NT) {
    const int row = e >> 3, c8 = (e & 7) * 8;
    *(uint4*)&l[row * BPAD + c8] = *(const uint4*)&g[row * 64 + c8];
  }
}

// fp32 global 64x64 -> split bf16 A-layout LDS, NT threads
__device__ __forceinline__ void split_stage(const float* __restrict__ g,
                                            ushort_t* __restrict__ Ah,
                                            ushort_t* __restrict__ Al, int tid, int NT) {
  for (int flat = tid * 4; flat < 4096; flat += NT * 4) {
    const int row = flat >> 6, col = flat & 63;
    const float4 v = *(const float4*)&g[flat];
    ushort_t h0 = f2bf(v.x), h1 = f2bf(v.y), h2 = f2bf(v.z), h3 = f2bf(v.w);
    ushort_t l0 = f2bf(v.x - bfhi(v.x)), l1 = f2bf(v.y - bfhi(v.y));
    ushort_t l2 = f2bf(v.z - bfhi(v.z)), l3 = f2bf(v.w - bfhi(v.w));
    uint2 hp, lp;
    hp.x = (unsigned)h0 | ((unsigned)h1 << 16); hp.y = (unsigned)h2 | ((unsigned)h3 << 16);
    lp.x = (unsigned)l0 | ((unsigned)l1 << 16); lp.y = (unsigned)l2 | ((unsigned)l3 << 16);
    *(uint2*)&Ah[row * BPAD + col] = hp;
    *(uint2*)&Al[row * BPAD + col] = lp;
  }
}

// ---------------------------------------------------------------------------
// K1: one block, 1024 threads (16 waves). fp32 recursive-doubling inverse of
// lower-tri M; A_bar = 2*Minv - I; 11 MFMA split-bf16 squarings, ping/pong
// double-buffered (ONE barrier per squaring). Exports S_j / S_j^T / Minv.
// ---------------------------------------------------------------------------
__global__ __launch_bounds__(1024) void k_setup(const float* __restrict__ A,
                                                const float* __restrict__ logdt,
                                                float* __restrict__ ws) {
  __shared__ __align__(16) char SM[73728];
  float* Msh = (float*)SM;                    // 64*65 fp32 (0..16639)
  float* Tm  = (float*)(SM + 16640);          // 64*65 fp32 (..33279)
  float* tmpb = (float*)(SM + 33280);         // 1024 fp32 (..37375)
  ushort_t* ping = (ushort_t*)SM;             // 4 x ARR (0..36863) overlays M/Tm
  ushort_t* pong = (ushort_t*)(SM + 36864);   // 4 x ARR (36864..73727)
  const int tid = threadIdx.x;
  const int w = tid >> 6, lane = tid & 63;
  const int mt = w >> 2, nt = w & 3;
  const int NT = 1024;

  const float hdt = 0.5f * expf(logdt[0]);
  for (int idx = tid; idx < 4096; idx += NT) {
    const int i = idx >> 6, j = idx & 63;
    Msh[i * 65 + j] = ((i == j) ? 1.f : 0.f) - hdt * A[idx];
    Tm[i * 65 + j] = 0.f;
  }
  __syncthreads();
  if (tid < 64) Tm[tid * 65 + tid] = 1.0f / Msh[tid * 65 + tid];
  __syncthreads();
  for (int lb = 0; lb < 6; ++lb) {
    const int b = 1 << lb;
    const int E = 32 * b;
    for (int e = tid; e < E; e += NT) {
      const int rem = e & (b * b - 1);
      const int p = e >> (2 * lb);
      const int i = rem >> lb, j = rem & (b - 1);
      const int c0 = p << (lb + 1), r0 = c0 + b;
      float s = 0.f;
      for (int k = 0; k < b; ++k)
        s += Msh[(r0 + i) * 65 + c0 + k] * Tm[(c0 + k) * 65 + c0 + j];
      tmpb[e] = s;
    }
    __syncthreads();
    for (int e = tid; e < E; e += NT) {
      const int rem = e & (b * b - 1);
      const int p = e >> (2 * lb);
      const int i = rem >> lb, j = rem & (b - 1);
      const int c0 = p << (lb + 1), r0 = c0 + b;
      float s = 0.f;
      const float* tp = &tmpb[e - rem];
      for (int k = 0; k < b; ++k)
        s += Tm[(r0 + i) * 65 + r0 + k] * tp[k * b + j];
      Tm[(r0 + i) * 65 + c0 + j] = -s;
    }
    __syncthreads();
  }

  // Export Minv; stash values in regs (ping overlays Tm below).
  {
    ushort_t* MvH = usp(ws, WS_MV);
    ushort_t* MvL = usp(ws, WS_MV + 2048);
    float mv[4];
#pragma unroll
    for (int t4 = 0; t4 < 4; ++t4) {
      const int idx = tid + NT * t4;
      const float m = Tm[(idx >> 6) * 65 + (idx & 63)];
      mv[t4] = m;
      MvH[idx] = f2bf(m); MvL[idx] = f2bf(m - bfhi(m));
    }
    __syncthreads();  // all Tm reads done before ping overwrites it
#pragma unroll
    for (int t4 = 0; t4 < 4; ++t4) {
      const int idx = tid + NT * t4;
      const int i = idx >> 6, j = idx & 63;
      const float v = 2.f * mv[t4] - ((i == j) ? 1.f : 0.f);
      const ushort_t h = f2bf(v), l2 = f2bf(v - bfhi(v));
      ping[0 * ARR + i * BPAD + j] = h; ping[1 * ARR + i * BPAD + j] = l2;
      ping[2 * ARR + j * BPAD + i] = h; ping[3 * ARR + j * BPAD + i] = l2;
    }
  }
  __syncthreads();
  cp_l2w(ping + 0 * ARR, usp(ws, WS_SPL + 0), tid, NT);
  cp_l2w(ping + 1 * ARR, usp(ws, WS_SPL + 2048), tid, NT);
  cp_l2w(ping + 2 * ARR, usp(ws, WS_SPL + 4096), tid, NT);
  cp_l2w(ping + 3 * ARR, usp(ws, WS_SPL + 6144), tid, NT);

  ushort_t* cur = ping;
  ushort_t* nxt = pong;
  for (int sj = 1; sj < 12; ++sj) {
    // reads cur (shared with the concurrent export of cur: both read-only)
    f32x4v acc;
    mm_frag16(cur, cur + ARR, cur + 2 * ARR, cur + 3 * ARR, mt, nt, lane, acc);
    dstore_lds16(acc, nxt, nxt + ARR, nxt + 2 * ARR, nxt + 3 * ARR, mt, nt, lane);
    __syncthreads();  // nxt complete; everyone done reading cur
    const int base = WS_SPL + sj * 8192;
    cp_l2w(nxt + 0 * ARR, usp(ws, base + 0), tid, NT);
    cp_l2w(nxt + 1 * ARR, usp(ws, base + 2048), tid, NT);
    cp_l2w(nxt + 2 * ARR, usp(ws, base + 4096), tid, NT);
    cp_l2w(nxt + 3 * ARR, usp(ws, base + 6144), tid, NT);
    ushort_t* t = cur; cur = nxt; nxt = t;
  }
}

// ---------------------------------------------------------------------------
// K2: 144 blocks x 1024 (16 waves).
//  p in [0,64):   Gt_r = (A^r)^T split  (product over set bits, MFMA)
//  p in [64,128): H_q  = A^(64q) split  (row-major)
//  p in [128,144): B_bar chunk = dt * B @ Minv^T (MFMA, fp32 out)
// ---------------------------------------------------------------------------
__global__ __launch_bounds__(1024) void k_powers(const float* __restrict__ Bg,
                                                 const float* __restrict__ logdt,
                                                 float* __restrict__ ws) {
  __shared__ __align__(16) ushort_t SMp[4 * ARR];  // 36.9 KB
  ushort_t* ca  = SMp;            // 2 arrays (hi,lo)
  ushort_t* Bst = SMp + 2 * ARR;  // 2 arrays (staged Bt operand / Gt result)
  const int p = blockIdx.x, tid = threadIdx.x;
  const int w = tid >> 6, lane = tid & 63;
  const int mt = w >> 2, nt = w & 3;
  const int NT = 1024;

  if (p < 128) {
    const int chain = p >> 6, r = p & 63;
    ushort_t* dstH = usp(ws, (chain ? WS_H : WS_GT) + r * 4096);
    ushort_t* dstL = usp(ws, (chain ? WS_H : WS_GT) + r * 4096 + 2048);
    if (r == 0) {  // identity
      for (int idx = tid; idx < 4096; idx += NT) {
        const int i = idx >> 6, j = idx & 63;
        dstH[idx] = (i == j) ? (ushort_t)0x3F80 : (ushort_t)0;
        dstL[idx] = 0;
      }
      return;
    }
    const int j0 = __ffs(r) - 1;
    if (r == (1 << j0)) {  // single bit: straight ws->ws copy
      const int sb = WS_SPL + (chain * 6 + j0) * 8192;
      const int src = chain ? sb : (sb + 4096);  // chain0: St, chain1: S
      const uint4* sh = (const uint4*)uspc(ws, src);
      const uint4* sl = (const uint4*)uspc(ws, src + 2048);
      uint4* dh = (uint4*)dstH;
      uint4* dl = (uint4*)dstL;
      for (int e = tid; e < 512; e += NT) { dh[e] = sh[e]; dl[e] = sl[e]; }
      return;
    }
    // multi-bit chain, single-buffered: ca accumulates product in A-layout
    {
      const int sb0 = WS_SPL + (chain * 6 + j0) * 8192;
      cp_w2l(uspc(ws, sb0 + 0), ca, tid, NT);
      cp_w2l(uspc(ws, sb0 + 2048), ca + ARR, tid, NT);
    }
    for (int j = j0 + 1; j < 6; ++j) {
      if ((r >> j) & 1) {
        __syncthreads();  // ca writes done (initial cp or prior dstore); Bst reads done
        const int sb = WS_SPL + (chain * 6 + j) * 8192;
        cp_w2l(uspc(ws, sb + 4096), Bst, tid, NT);        // St_j hi
        cp_w2l(uspc(ws, sb + 6144), Bst + ARR, tid, NT);  // St_j lo
        __syncthreads();
        f32x4v acc;
        mm_frag16(ca, ca + ARR, Bst, Bst + ARR, mt, nt, lane, acc);
        __syncthreads();  // all reads done before overwrite
        const bool last = ((r >> (j + 1)) == 0);
        if (last && chain == 0)
          dstore_Bt16(acc, Bst, Bst + ARR, mt, nt, lane);  // Bst dead -> holds Gt
        else
          dstore_A16(acc, ca, ca + ARR, mt, nt, lane);
      }
    }
    __syncthreads();
    if (chain == 0) { cp_l2w(Bst, dstH, tid, NT); cp_l2w(Bst + ARR, dstL, tid, NT); }
    else            { cp_l2w(ca, dstH, tid, NT);  cp_l2w(ca + ARR, dstL, tid, NT); }
  } else {
    // B_bar chunk: dt * B_chunk @ Minv^T. Bt-frag rows = Minv rows.
    const int d0 = (p - 128) * 64;
    const float dtv = expf(logdt[0]);
    split_stage(Bg + d0 * 64, ca, ca + ARR, tid, NT);
    cp_w2l(uspc(ws, WS_MV), Bst, tid, NT);
    cp_w2l(uspc(ws, WS_MV + 2048), Bst + ARR, tid, NT);
    __syncthreads();
    f32x4v acc;
    mm_frag16(ca, ca + ARR, Bst, Bst + ARR, mt, nt, lane, acc);
    const int lm = lane & 15, quad = lane >> 4;
    float* od = ws + WS_BBAR + d0 * 64;
#pragma unroll
    for (int reg = 0; reg < 4; ++reg)
      od[(16 * mt + 4 * quad + reg) * 64 + 16 * nt + lm] = dtv * acc[reg];
  }
}

// ---------------------------------------------------------------------------
// K3: 2048 blocks x 256. (unchanged R9) Block = (chain, rr, dch).
//  chain0: W[d0..][rr][j] = sum_n C[d,n] A^rr[n,j]   (Bt = Gt_rr, pre-split)
//  chain1: X[d0..][rr][j] = sum_k Bbar[d,k] H_rr[j,k] (Bt = H_rr, pre-split)
// LDS 36.9 KB -> 4 blocks/CU.
// ---------------------------------------------------------------------------
__global__ __launch_bounds__(256) void k_expand(const float* __restrict__ Cg,
                                                float* __restrict__ ws) {
  __shared__ __align__(16) ushort_t SMe[4 * ARR];
  ushort_t* Asp = SMe;            // hi, lo
  ushort_t* Bsp = SMe + 2 * ARR;  // hi, lo
  const int p = blockIdx.x, tid = threadIdx.x;
  const int chain = p >> 10, rr = (p >> 4) & 63, dch = p & 15;
  const int w = tid >> 6, lane = tid & 63;
  const int d0 = dch * 64;

  split_stage(chain ? (ws + WS_BBAR + d0 * 64) : (Cg + d0 * 64), Asp, Asp + ARR, tid, 256);
  const int mb = (chain ? WS_H : WS_GT) + rr * 4096;
  cp_w2l(uspc(ws, mb + 0), Bsp, tid, 256);
  cp_w2l(uspc(ws, mb + 2048), Bsp + ARR, tid, 256);
  __syncthreads();

  f32x4v acc[4];
  mm_frag(Asp, Asp + ARR, Bsp, Bsp + ARR, w, lane, acc);

  const int lm = lane & 15, quad = lane >> 4;
  float* dst = ws + (chain ? WS_X : WS_W) + d0 * 4096 + rr * 64;
#pragma unroll
  for (int nt = 0; nt < 4; ++nt)
#pragma unroll
    for (int reg = 0; reg < 4; ++reg)
      dst[(16 * w + 4 * quad + reg) * 4096 + 16 * nt + lm] = acc[nt][reg];
}

// ---------------------------------------------------------------------------
// K4: 1024 blocks x 256, one block per d — MFMA split-bf16 (unchanged R9).
// ---------------------------------------------------------------------------
__global__ __launch_bounds__(256) void k_contract(const float* __restrict__ Dg,
                                                  const float* __restrict__ ws,
                                                  float* __restrict__ out) {
  __shared__ __align__(16) ushort_t XhiL[64 * BPAD];
  __shared__ __align__(16) ushort_t XloL[64 * BPAD];
  __shared__ __align__(16) ushort_t WhiL[64 * BPAD];
  __shared__ __align__(16) ushort_t WloL[64 * BPAD];
  const int d = blockIdx.x, tid = threadIdx.x;
  const float* Wg = ws + WS_W + d * 4096;
  const float* Xg = ws + WS_X + d * 4096;

#pragma unroll
  for (int j = 0; j < 4; ++j) {
    const int flat = j * 1024 + tid * 4;
    const int row = flat >> 6, col = flat & 63;
    const float4 wv = *(const float4*)&Wg[flat];
    const float4 xv = *(const float4*)&Xg[flat];
    const int o = row * BPAD + col;
#pragma unroll
    for (int s = 0; s < 2; ++s) {
      const float4 v = s ? xv : wv;
      ushort_t h0 = f2bf(v.x), h1 = f2bf(v.y), h2 = f2bf(v.z), h3 = f2bf(v.w);
      ushort_t l0 = f2bf(v.x - bfhi(v.x)), l1 = f2bf(v.y - bfhi(v.y));
      ushort_t l2 = f2bf(v.z - bfhi(v.z)), l3 = f2bf(v.w - bfhi(v.w));
      uint2 hp, lp;
      hp.x = (unsigned)h0 | ((unsigned)h1 << 16); hp.y = (unsigned)h2 | ((unsigned)h3 << 16);
      lp.x = (unsigned)l0 | ((unsigned)l1 << 16); lp.y = (unsigned)l2 | ((unsigned)l3 << 16);
      *(uint2*)&(s ? XhiL : WhiL)[o] = hp;
      *(uint2*)&(s ? XloL : WloL)[o] = lp;
    }
  }
  __syncthreads();

  const int w = tid >> 6, lane = tid & 63;
  const int lm = lane & 15, quad = lane >> 4;
  const int qrow = 16 * w + lm;
  const int koff = quad * 8;

  f32x4v acc[4];
#pragma unroll
  for (int nt = 0; nt < 4; ++nt) { acc[nt][0] = 0.f; acc[nt][1] = 0.f; acc[nt][2] = 0.f; acc[nt][3] = 0.f; }

#pragma unroll
  for (int kc = 0; kc < 64; kc += 32) {
    const bf16x8 ahi = *(const bf16x8*)&XhiL[qrow * BPAD + kc + koff];
    const bf16x8 alo = *(const bf16x8*)&XloL[qrow * BPAD + kc + koff];
#pragma unroll
    for (int nt = 0; nt < 4; ++nt) {
      const int rrow = 16 * nt + lm;
      const bf16x8 bhi = *(const bf16x8*)&WhiL[rrow * BPAD + kc + koff];
      const bf16x8 blo = *(const bf16x8*)&WloL[rrow * BPAD + kc + koff];
      acc[nt] = __builtin_amdgcn_mfma_f32_16x16x32_bf16(ahi, bhi, acc[nt], 0, 0, 0);
      acc[nt] = __builtin_amdgcn_mfma_f32_16x16x32_bf16(ahi, blo, acc[nt], 0, 0, 0);
      acc[nt] = __builtin_amdgcn_mfma_f32_16x16x32_bf16(alo, bhi, acc[nt], 0, 0, 0);
    }
  }

  if (tid == 0) acc[0][0] += Dg[d];

  float* od = out + d * 4096;
#pragma unroll
  for (int nt = 0; nt < 4; ++nt) {
#pragma unroll
    for (int reg = 0; reg < 4; ++reg) {
      const int q = 16 * w + quad * 4 + reg;
      od[q * 64 + 16 * nt + lm] = acc[nt][reg];
    }
  }
}

extern "C" void kernel_launch(void* const* d_in, const int* in_sizes, int n_in,
                              void* d_out, int out_size, void* d_ws, size_t ws_size,
                              hipStream_t stream) {
  const float* A     = (const float*)d_in[0];  // A_ct 64x64
  const float* B     = (const float*)d_in[1];  // 1024x64
  const float* C     = (const float*)d_in[2];  // 1024x64
  const float* Dv    = (const float*)d_in[3];  // 1024
  const float* logdt = (const float*)d_in[4];  // scalar
  float* ws  = (float*)d_ws;
  float* out = (float*)d_out;                  // 1024*4096 fp32

  hipLaunchKernelGGL(k_setup,    dim3(1),    dim3(1024), 0, stream, A, logdt, ws);
  hipLaunchKernelGGL(k_powers,   dim3(144),  dim3(1024), 0, stream, B, logdt, ws);
  hipLaunchKernelGGL(k_expand,   dim3(2048), dim3(256),  0, stream, C, ws);
  hipLaunchKernelGGL(k_contract, dim3(1024), dim3(256),  0, stream, Dv, ws, out);
}

// Round 3
// 114.911 us; speedup vs baseline: 4.3979x; 1.0407x over previous
//
#include <hip/hip_runtime.h>
#include <math.h>

// HiPPO-LegS kernel: K[d, l] = C[d]^T A_bar^l B_bar[d], D=1024, N=64, L=4096.
// l = 64q + r decomposition; G_r = A_bar^r, H_q = (A_bar^64)^q via squarings
// S_j = A_bar^(2^j).  All products: mfma_f32_16x16x32_bf16 split-bf16 3-term.
// Round 12: k_setup MERGED into k_powers -> k_prologue (144 blocks x 1024).
// Each block computes the fp32 triangular inverse + its own squaring ladder
// locally (in-place, 2 barriers/level) with chain products interleaved at the
// set-bit levels; final product exported from registers. Removes one kernel
// launch + all WS_SPL/WS_MV round-trips. Math is bit-identical to R11
// (absmax must stay 0.0002441406). k_expand/k_contract byte-identical to R11.

#define BPAD 72  // bf16 LDS row stride in ushorts (144 B)
#define ARR (64 * BPAD)

// ws layout (float offsets). SPL/MV now unused (kept for doc).
#define WS_BBAR   16                      // 1024x64 fp32
#define WS_SPL    65552                   // (unused since R12)
#define WS_MV     (WS_SPL + 12*8192)      // (unused since R12)
#define WS_GT     (WS_MV + 4096)          // 64 x 4096 (hi 2048 | lo 2048)
#define WS_H      (WS_GT + 64*4096)       // 64 x 4096 (hi | lo)
#define WS_W      (WS_H + 64*4096)        // [d][r][n] fp32
#define WS_X      (WS_W + 1024*4096)      // [d][q][n] fp32

using bf16x8 = __attribute__((ext_vector_type(8))) short;
using f32x4v = __attribute__((ext_vector_type(4))) float;
typedef unsigned short ushort_t;

__device__ __forceinline__ ushort_t f2bf(float x) {
  unsigned u = __builtin_bit_cast(unsigned, x);
  return (ushort_t)((u + 0x7FFFu + ((u >> 16) & 1u)) >> 16);
}
__device__ __forceinline__ float bfhi(float x) {
  unsigned u = __builtin_bit_cast(unsigned, x);
  unsigned r = (u + 0x7FFFu + ((u >> 16) & 1u)) & 0xFFFF0000u;
  return __builtin_bit_cast(float, r);
}
__device__ __forceinline__ ushort_t* usp(float* ws, int foff) {
  return (ushort_t*)(ws + foff);
}
__device__ __forceinline__ const ushort_t* uspc(const float* ws, int foff) {
  return (const ushort_t*)(ws + foff);
}

// ---- 4-wave MFMA 64x64x64 (k_expand/k_contract path) ----
__device__ __forceinline__ void mm_frag(const ushort_t* __restrict__ Ah,
                                        const ushort_t* __restrict__ Al,
                                        const ushort_t* __restrict__ Bh,
                                        const ushort_t* __restrict__ Bl,
                                        int w, int lane, f32x4v acc[4]) {
  const int lm = lane & 15, quad = lane >> 4;
  const int ar = (16 * w + lm) * BPAD, ko = quad * 8;
#pragma unroll
  for (int nt = 0; nt < 4; ++nt) { acc[nt][0] = acc[nt][1] = acc[nt][2] = acc[nt][3] = 0.f; }
#pragma unroll
  for (int kc = 0; kc < 64; kc += 32) {
    const bf16x8 ahi = *(const bf16x8*)&Ah[ar + kc + ko];
    const bf16x8 alo = *(const bf16x8*)&Al[ar + kc + ko];
#pragma unroll
    for (int nt = 0; nt < 4; ++nt) {
      const int br = (16 * nt + lm) * BPAD + kc + ko;
      const bf16x8 bhi = *(const bf16x8*)&Bh[br];
      const bf16x8 blo = *(const bf16x8*)&Bl[br];
      acc[nt] = __builtin_amdgcn_mfma_f32_16x16x32_bf16(ahi, bhi, acc[nt], 0, 0, 0);
      acc[nt] = __builtin_amdgcn_mfma_f32_16x16x32_bf16(ahi, blo, acc[nt], 0, 0, 0);
      acc[nt] = __builtin_amdgcn_mfma_f32_16x16x32_bf16(alo, bhi, acc[nt], 0, 0, 0);
    }
  }
}

// ---- 16-wave MFMA 64x64x64: wave (mt,nt) owns one 16x16 tile, 6 MFMA ----
__device__ __forceinline__ void mm_frag16(const ushort_t* __restrict__ Ah,
                                          const ushort_t* __restrict__ Al,
                                          const ushort_t* __restrict__ Bh,
                                          const ushort_t* __restrict__ Bl,
                                          int mt, int nt, int lane, f32x4v& acc) {
  const int lm = lane & 15, quad = lane >> 4;
  const int ar = (16 * mt + lm) * BPAD, br = (16 * nt + lm) * BPAD, ko = quad * 8;
  acc[0] = acc[1] = acc[2] = acc[3] = 0.f;
#pragma unroll
  for (int kc = 0; kc < 64; kc += 32) {
    const bf16x8 ahi = *(const bf16x8*)&Ah[ar + kc + ko];
    const bf16x8 alo = *(const bf16x8*)&Al[ar + kc + ko];
    const bf16x8 bhi = *(const bf16x8*)&Bh[br + kc + ko];
    const bf16x8 blo = *(const bf16x8*)&Bl[br + kc + ko];
    acc = __builtin_amdgcn_mfma_f32_16x16x32_bf16(ahi, bhi, acc, 0, 0, 0);
    acc = __builtin_amdgcn_mfma_f32_16x16x32_bf16(ahi, blo, acc, 0, 0, 0);
    acc = __builtin_amdgcn_mfma_f32_16x16x32_bf16(alo, bhi, acc, 0, 0, 0);
  }
}

// 16-wave D store -> split bf16, BOTH layouts (in-place squaring).
__device__ __forceinline__ void dstore_lds16(const f32x4v& acc,
                                             ushort_t* __restrict__ Ah, ushort_t* __restrict__ Al,
                                             ushort_t* __restrict__ Bth, ushort_t* __restrict__ Btl,
                                             int mt, int nt, int lane) {
  const int lm = lane & 15, quad = lane >> 4;
  const int m0 = 16 * mt + 4 * quad;
  const int n = 16 * nt + lm;
  ushort_t h[4], l[4];
#pragma unroll
  for (int reg = 0; reg < 4; ++reg) {
    const float x = acc[reg];
    h[reg] = f2bf(x); l[reg] = f2bf(x - bfhi(x));
    Ah[(m0 + reg) * BPAD + n] = h[reg];
    Al[(m0 + reg) * BPAD + n] = l[reg];
  }
  uint2 hp, lp;
  hp.x = (unsigned)h[0] | ((unsigned)h[1] << 16);
  hp.y = (unsigned)h[2] | ((unsigned)h[3] << 16);
  lp.x = (unsigned)l[0] | ((unsigned)l[1] << 16);
  lp.y = (unsigned)l[2] | ((unsigned)l[3] << 16);
  *(uint2*)&Bth[n * BPAD + m0] = hp;
  *(uint2*)&Btl[n * BPAD + m0] = lp;
}

// 16-wave D store -> A-layout only (chain intermediates).
__device__ __forceinline__ void dstore_A16(const f32x4v& acc,
                                           ushort_t* __restrict__ Ah, ushort_t* __restrict__ Al,
                                           int mt, int nt, int lane) {
  const int lm = lane & 15, quad = lane >> 4;
  const int m0 = 16 * mt + 4 * quad;
  const int n = 16 * nt + lm;
#pragma unroll
  for (int reg = 0; reg < 4; ++reg) {
    const float x = acc[reg];
    Ah[(m0 + reg) * BPAD + n] = f2bf(x);
    Al[(m0 + reg) * BPAD + n] = f2bf(x - bfhi(x));
  }
}

// packed 64x64 ushort ws region <-> padded LDS (BPAD), NT threads
__device__ __forceinline__ void cp_l2w(const ushort_t* __restrict__ l,
                                       ushort_t* __restrict__ g, int tid, int NT) {
  for (int e = tid; e < 512; e += NT) {
    const int row = e >> 3, c8 = (e & 7) * 8;
    *(uint4*)&g[row * 64 + c8] = *(const uint4*)&l[row * BPAD + c8];
  }
}
__device__ __forceinline__ void cp_w2l(const ushort_t* __restrict__ g,
                                       ushort_t* __restrict__ l, int tid, int NT) {
  for (int e = tid; e < 512; e += NT) {
    const int row = e >> 3, c8 = (e & 7) * 8;
    *(uint4*)&l[row * BPAD + c8] = *(const uint4*)&g[row * 64 + c8];
  }
}

// fp32 global 64x64 -> split bf16 A-layout LDS, NT threads
__device__ __forceinline__ void split_stage(const float* __restrict__ g,
                                            ushort_t* __restrict__ Ah,
                                            ushort_t* __restrict__ Al, int tid, int NT) {
  for (int flat = tid * 4; flat < 4096; flat += NT * 4) {
    const int row = flat >> 6, col = flat & 63;
    const float4 v = *(const float4*)&g[flat];
    ushort_t h0 = f2bf(v.x), h1 = f2bf(v.y), h2 = f2bf(v.z), h3 = f2bf(v.w);
    ushort_t l0 = f2bf(v.x - bfhi(v.x)), l1 = f2bf(v.y - bfhi(v.y));
    ushort_t l2 = f2bf(v.z - bfhi(v.z)), l3 = f2bf(v.w - bfhi(v.w));
    uint2 hp, lp;
    hp.x = (unsigned)h0 | ((unsigned)h1 << 16); hp.y = (unsigned)h2 | ((unsigned)h3 << 16);
    lp.x = (unsigned)l0 | ((unsigned)l1 << 16); lp.y = (unsigned)l2 | ((unsigned)l3 << 16);
    *(uint2*)&Ah[row * BPAD + col] = hp;
    *(uint2*)&Al[row * BPAD + col] = lp;
  }
}

// ---------------------------------------------------------------------------
// K1: k_prologue, 144 blocks x 1024 (16 waves). Every block:
//   fp32 recursive-doubling inverse of lower-tri M (LDS, 1024 threads);
//   p in [0,64):   Gt_r = (A^r)^T   — local squaring ladder S_0..S_topbit(r),
//                  products interleaved at set-bit levels, in-place.
//   p in [64,128): H_q  = A^(64q)   — same, absolute levels 6..6+topbit(q).
//   p in [128,144): B_bar chunk = dt * B @ Minv^T (local Minv, MFMA).
// LDS: inverse {Msh,Tm,tmpb} = 37376 B overlaid by ping(4xARR=36864) ;
//      ca (2xARR=18432) at 36864. Total 55296 B static.
// ---------------------------------------------------------------------------
__global__ __launch_bounds__(1024) void k_prologue(const float* __restrict__ A,
                                                   const float* __restrict__ Bg,
                                                   const float* __restrict__ logdt,
                                                   float* __restrict__ ws) {
  __shared__ __align__(16) char SM[55296];
  float* Msh  = (float*)SM;                    // 64*65 fp32 (0..16639)
  float* Tm   = (float*)(SM + 16640);          // 64*65 fp32 (..33279)
  float* tmpb = (float*)(SM + 33280);          // 1024 fp32 (..37375, dead post-inv)
  ushort_t* ping = (ushort_t*)SM;              // 4 x ARR (0..36863)
  ushort_t* ca   = (ushort_t*)(SM + 36864);    // 2 x ARR (36864..55295)
  const int p = blockIdx.x, tid = threadIdx.x;
  const int w = tid >> 6, lane = tid & 63;
  const int mt = w >> 2, nt4 = w & 3;
  const int lm = lane & 15, quad = lane >> 4;
  const int NT = 1024;

  const int chain = (p < 128) ? (p >> 6) : 0;
  const int rq = p & 63;

  if (p < 128 && rq == 0) {  // identity export, no inverse needed
    ushort_t* dstH = usp(ws, (chain ? WS_H : WS_GT));
    ushort_t* dstL = dstH + 4096;
    for (int idx = tid; idx < 4096; idx += NT) {
      const int i = idx >> 6, j = idx & 63;
      dstH[idx] = (i == j) ? (ushort_t)0x3F80 : (ushort_t)0;
      dstL[idx] = 0;
    }
    return;
  }

  // ---- fp32 recursive-doubling inverse of M = I - (dt/2) A (lower-tri) ----
  const float hdt = 0.5f * expf(logdt[0]);
  for (int idx = tid; idx < 4096; idx += NT) {
    const int i = idx >> 6, j = idx & 63;
    Msh[i * 65 + j] = ((i == j) ? 1.f : 0.f) - hdt * A[idx];
    Tm[i * 65 + j] = 0.f;
  }
  __syncthreads();
  if (tid < 64) Tm[tid * 65 + tid] = 1.0f / Msh[tid * 65 + tid];
  __syncthreads();
  for (int lb = 0; lb < 6; ++lb) {
    const int b = 1 << lb;
    const int E = 32 * b;
    for (int e = tid; e < E; e += NT) {
      const int rem = e & (b * b - 1);
      const int pp = e >> (2 * lb);
      const int i = rem >> lb, j = rem & (b - 1);
      const int c0 = pp << (lb + 1), r0 = c0 + b;
      float s = 0.f;
      for (int k = 0; k < b; ++k)
        s += Msh[(r0 + i) * 65 + c0 + k] * Tm[(c0 + k) * 65 + c0 + j];
      tmpb[e] = s;
    }
    __syncthreads();
    for (int e = tid; e < E; e += NT) {
      const int rem = e & (b * b - 1);
      const int pp = e >> (2 * lb);
      const int i = rem >> lb, j = rem & (b - 1);
      const int c0 = pp << (lb + 1), r0 = c0 + b;
      float s = 0.f;
      const float* tp = &tmpb[e - rem];
      for (int k = 0; k < b; ++k)
        s += Tm[(r0 + i) * 65 + r0 + k] * tp[k * b + j];
      Tm[(r0 + i) * 65 + c0 + j] = -s;
    }
    __syncthreads();
  }

  // stash Minv in regs (ping overlays Tm below)
  float mv[4];
#pragma unroll
  for (int t4 = 0; t4 < 4; ++t4) {
    const int idx = tid + NT * t4;
    mv[t4] = Tm[(idx >> 6) * 65 + (idx & 63)];
  }
  __syncthreads();  // all Tm reads done before ping overwrites it

  if (p >= 128) {
    // ---- B_bar chunk: dt * B_chunk @ Minv^T (Bt operand = Minv rows) ----
    const int d0 = (p - 128) * 64;
    const float dtv = expf(logdt[0]);
    ushort_t* Bh = ping;           ushort_t* Bl = ping + ARR;
    ushort_t* Mh = ping + 2 * ARR; ushort_t* Ml = ping + 3 * ARR;
    split_stage(Bg + d0 * 64, Bh, Bl, tid, NT);
#pragma unroll
    for (int t4 = 0; t4 < 4; ++t4) {
      const int idx = tid + NT * t4;
      const int i = idx >> 6, j = idx & 63;
      const float m = mv[t4];
      Mh[i * BPAD + j] = f2bf(m);
      Ml[i * BPAD + j] = f2bf(m - bfhi(m));
    }
    __syncthreads();
    f32x4v acc;
    mm_frag16(Bh, Bl, Mh, Ml, mt, nt4, lane, acc);
    float* od = ws + WS_BBAR + d0 * 64;
#pragma unroll
    for (int reg = 0; reg < 4; ++reg)
      od[(16 * mt + 4 * quad + reg) * 64 + 16 * nt4 + lm] = dtv * acc[reg];
    return;
  }

  // ---- chain blocks: local squaring ladder + interleaved products ----
  const int base6 = chain * 6;
  const int j0   = (__ffs(rq) - 1) + base6;
  const int jmax = (31 - __clz((unsigned)rq)) + base6;
  const bool single = (j0 == jmax);

  // ping = A_bar = 2*Minv - I, in both layouts (split hi/lo)
#pragma unroll
  for (int t4 = 0; t4 < 4; ++t4) {
    const int idx = tid + NT * t4;
    const int i = idx >> 6, j = idx & 63;
    const float v = 2.f * mv[t4] - ((i == j) ? 1.f : 0.f);
    const ushort_t h = f2bf(v), l2 = f2bf(v - bfhi(v));
    ping[0 * ARR + i * BPAD + j] = h; ping[1 * ARR + i * BPAD + j] = l2;
    ping[2 * ARR + j * BPAD + i] = h; ping[3 * ARR + j * BPAD + i] = l2;
  }
  __syncthreads();

  ushort_t* cur = ping;            // S_j, in-place, all 4 arrays
  ushort_t* cah = ca;              // accumulated product, A-layout hi
  ushort_t* cal = ca + ARR;        //                       A-layout lo

  for (int j = 0; j <= jmax; ++j) {
    // invariant: cur holds S_j complete (barrier'd)
    const bool isprod = (j > j0) && ((rq >> (j - base6)) & 1);
    const bool dosq = (j < jmax);
    if (j == j0 && !single) {
      // ca = S_j0 (A-layout hi/lo copy)
      const int arr = tid >> 9, ei = tid & 511;
      const int row = ei >> 3, c8 = (ei & 7) * 8;
      *(uint4*)&ca[arr * ARR + row * BPAD + c8] =
          *(const uint4*)&cur[arr * ARR + row * BPAD + c8];
    }
    f32x4v accp, accs;
    if (isprod) mm_frag16(cah, cal, cur + 2 * ARR, cur + 3 * ARR, mt, nt4, lane, accp);
    if (dosq)   mm_frag16(cur, cur + ARR, cur + 2 * ARR, cur + 3 * ARR, mt, nt4, lane, accs);
    __syncthreads();  // all reads (and the j0-copy writes) done
    if (isprod && !dosq) {
      // final product: export straight from registers
      const int m0 = 16 * mt + 4 * quad, n = 16 * nt4 + lm;
      ushort_t h[4], l[4];
#pragma unroll
      for (int reg = 0; reg < 4; ++reg) {
        const float x = accp[reg];
        h[reg] = f2bf(x); l[reg] = f2bf(x - bfhi(x));
      }
      if (chain == 0) {  // Gt = (product)^T : row n, cols m0..m0+3, packed
        ushort_t* dstH = usp(ws, WS_GT + rq * 4096);
        ushort_t* dstL = dstH + 4096;
        uint2 hp, lp;
        hp.x = (unsigned)h[0] | ((unsigned)h[1] << 16);
        hp.y = (unsigned)h[2] | ((unsigned)h[3] << 16);
        lp.x = (unsigned)l[0] | ((unsigned)l[1] << 16);
        lp.y = (unsigned)l[2] | ((unsigned)l[3] << 16);
        *(uint2*)&dstH[n * 64 + m0] = hp;
        *(uint2*)&dstL[n * 64 + m0] = lp;
      } else {           // H row-major: rows m0..m0+3, col n, scalar
        ushort_t* dstH = usp(ws, WS_H + rq * 4096);
        ushort_t* dstL = dstH + 4096;
#pragma unroll
        for (int reg = 0; reg < 4; ++reg) {
          dstH[(m0 + reg) * 64 + n] = h[reg];
          dstL[(m0 + reg) * 64 + n] = l[reg];
        }
      }
      return;
    }
    if (isprod) dstore_A16(accp, cah, cal, mt, nt4, lane);
    if (dosq)   dstore_lds16(accs, cur, cur + ARR, cur + 2 * ARR, cur + 3 * ARR,
                             mt, nt4, lane);
    __syncthreads();
  }

  // single-bit chains: export S_{j0} (chain0 transposed = Bt arrays)
  if (chain == 0) {
    ushort_t* dstH = usp(ws, WS_GT + rq * 4096);
    ushort_t* dstL = dstH + 4096;
    cp_l2w(cur + 2 * ARR, dstH, tid, NT);
    cp_l2w(cur + 3 * ARR, dstL, tid, NT);
  } else {
    ushort_t* dstH = usp(ws, WS_H + rq * 4096);
    ushort_t* dstL = dstH + 4096;
    cp_l2w(cur, dstH, tid, NT);
    cp_l2w(cur + ARR, dstL, tid, NT);
  }
}

// ---------------------------------------------------------------------------
// K2: 2048 blocks x 256. (unchanged) Block = (chain, rr, dch).
//  chain0: W[d0..][rr][j] = sum_n C[d,n] A^rr[n,j]   (Bt = Gt_rr, pre-split)
//  chain1: X[d0..][rr][j] = sum_k Bbar[d,k] H_rr[j,k] (Bt = H_rr, pre-split)
// LDS 36.9 KB -> 4 blocks/CU.
// ---------------------------------------------------------------------------
__global__ __launch_bounds__(256) void k_expand(const float* __restrict__ Cg,
                                                float* __restrict__ ws) {
  __shared__ __align__(16) ushort_t SMe[4 * ARR];
  ushort_t* Asp = SMe;            // hi, lo
  ushort_t* Bsp = SMe + 2 * ARR;  // hi, lo
  const int p = blockIdx.x, tid = threadIdx.x;
  const int chain = p >> 10, rr = (p >> 4) & 63, dch = p & 15;
  const int w = tid >> 6, lane = tid & 63;
  const int d0 = dch * 64;

  split_stage(chain ? (ws + WS_BBAR + d0 * 64) : (Cg + d0 * 64), Asp, Asp + ARR, tid, 256);
  const int mb = (chain ? WS_H : WS_GT) + rr * 4096;
  cp_w2l(uspc(ws, mb + 0), Bsp, tid, 256);
  cp_w2l(uspc(ws, mb + 2048), Bsp + ARR, tid, 256);
  __syncthreads();

  f32x4v acc[4];
  mm_frag(Asp, Asp + ARR, Bsp, Bsp + ARR, w, lane, acc);

  const int lm = lane & 15, quad = lane >> 4;
  float* dst = ws + (chain ? WS_X : WS_W) + d0 * 4096 + rr * 64;
#pragma unroll
  for (int nt = 0; nt < 4; ++nt)
#pragma unroll
    for (int reg = 0; reg < 4; ++reg)
      dst[(16 * w + 4 * quad + reg) * 4096 + 16 * nt + lm] = acc[nt][reg];
}

// ---------------------------------------------------------------------------
// K3: 1024 blocks x 256, one block per d — MFMA split-bf16 (unchanged).
// ---------------------------------------------------------------------------
__global__ __launch_bounds__(256) void k_contract(const float* __restrict__ Dg,
                                                  const float* __restrict__ ws,
                                                  float* __restrict__ out) {
  __shared__ __align__(16) ushort_t XhiL[64 * BPAD];
  __shared__ __align__(16) ushort_t XloL[64 * BPAD];
  __shared__ __align__(16) ushort_t WhiL[64 * BPAD];
  __shared__ __align__(16) ushort_t WloL[64 * BPAD];
  const int d = blockIdx.x, tid = threadIdx.x;
  const float* Wg = ws + WS_W + d * 4096;
  const float* Xg = ws + WS_X + d * 4096;

#pragma unroll
  for (int j = 0; j < 4; ++j) {
    const int flat = j * 1024 + tid * 4;
    const int row = flat >> 6, col = flat & 63;
    const float4 wv = *(const float4*)&Wg[flat];
    const float4 xv = *(const float4*)&Xg[flat];
    const int o = row * BPAD + col;
#pragma unroll
    for (int s = 0; s < 2; ++s) {
      const float4 v = s ? xv : wv;
      ushort_t h0 = f2bf(v.x), h1 = f2bf(v.y), h2 = f2bf(v.z), h3 = f2bf(v.w);
      ushort_t l0 = f2bf(v.x - bfhi(v.x)), l1 = f2bf(v.y - bfhi(v.y));
      ushort_t l2 = f2bf(v.z - bfhi(v.z)), l3 = f2bf(v.w - bfhi(v.w));
      uint2 hp, lp;
      hp.x = (unsigned)h0 | ((unsigned)h1 << 16); hp.y = (unsigned)h2 | ((unsigned)h3 << 16);
      lp.x = (unsigned)l0 | ((unsigned)l1 << 16); lp.y = (unsigned)l2 | ((unsigned)l3 << 16);
      *(uint2*)&(s ? XhiL : WhiL)[o] = hp;
      *(uint2*)&(s ? XloL : WloL)[o] = lp;
    }
  }
  __syncthreads();

  const int w = tid >> 6, lane = tid & 63;
  const int lm = lane & 15, quad = lane >> 4;
  const int qrow = 16 * w + lm;
  const int koff = quad * 8;

  f32x4v acc[4];
#pragma unroll
  for (int nt = 0; nt < 4; ++nt) { acc[nt][0] = 0.f; acc[nt][1] = 0.f; acc[nt][2] = 0.f; acc[nt][3] = 0.f; }

#pragma unroll
  for (int kc = 0; kc < 64; kc += 32) {
    const bf16x8 ahi = *(const bf16x8*)&XhiL[qrow * BPAD + kc + koff];
    const bf16x8 alo = *(const bf16x8*)&XloL[qrow * BPAD + kc + koff];
#pragma unroll
    for (int nt = 0; nt < 4; ++nt) {
      const int rrow = 16 * nt + lm;
      const bf16x8 bhi = *(const bf16x8*)&WhiL[rrow * BPAD + kc + koff];
      const bf16x8 blo = *(const bf16x8*)&WloL[rrow * BPAD + kc + koff];
      acc[nt] = __builtin_amdgcn_mfma_f32_16x16x32_bf16(ahi, bhi, acc[nt], 0, 0, 0);
      acc[nt] = __builtin_amdgcn_mfma_f32_16x16x32_bf16(ahi, blo, acc[nt], 0, 0, 0);
      acc[nt] = __builtin_amdgcn_mfma_f32_16x16x32_bf16(alo, bhi, acc[nt], 0, 0, 0);
    }
  }

  if (tid == 0) acc[0][0] += Dg[d];

  float* od = out + d * 4096;
#pragma unroll
  for (int nt = 0; nt < 4; ++nt) {
#pragma unroll
    for (int reg = 0; reg < 4; ++reg) {
      const int q = 16 * w + quad * 4 + reg;
      od[q * 64 + 16 * nt + lm] = acc[nt][reg];
    }
  }
}

extern "C" void kernel_launch(void* const* d_in, const int* in_sizes, int n_in,
                              void* d_out, int out_size, void* d_ws, size_t ws_size,
                              hipStream_t stream) {
  const float* A     = (const float*)d_in[0];  // A_ct 64x64
  const float* B     = (const float*)d_in[1];  // 1024x64
  const float* C     = (const float*)d_in[2];  // 1024x64
  const float* Dv    = (const float*)d_in[3];  // 1024
  const float* logdt = (const float*)d_in[4];  // scalar
  float* ws  = (float*)d_ws;
  float* out = (float*)d_out;                  // 1024*4096 fp32

  hipLaunchKernelGGL(k_prologue, dim3(144),  dim3(1024), 0, stream, A, B, logdt, ws);
  hipLaunchKernelGGL(k_expand,   dim3(2048), dim3(256),  0, stream, C, ws);
  hipLaunchKernelGGL(k_contract, dim3(1024), dim3(256),  0, stream, Dv, ws, out);
}